// Round 3
// baseline (201.001 us; speedup 1.0000x reference)
//
#include <hip/hip_runtime.h>
#include <hip/hip_bf16.h>

#define DEV __device__ __forceinline__

typedef __attribute__((ext_vector_type(8))) short short8;
typedef __attribute__((ext_vector_type(4))) float f32x4;

constexpr int D   = 128;
constexpr int S   = 2048;
constexpr int Hh  = 4;
constexpr int DH  = 32;
// 1/sqrt(32) * log2(e): QK^T logits land directly in exp2 domain.
constexpr float QSCALE = 0.17677669529663687f * 1.4426950408889634f;
constexpr float EPSV = 1e-5f;

DEV unsigned short f2b(float f) {
  __hip_bfloat16 h = __float2bfloat16(f);
  return *reinterpret_cast<unsigned short*>(&h);
}
DEV unsigned pack2(float a, float b) {
  return (unsigned)f2b(a) | ((unsigned)f2b(b) << 16);
}

// ---------------- prep: x -> bf16, weights -> bf16 transposed ----------------
__global__ __launch_bounds__(256) void prep_kernel(
    const float* __restrict__ x,
    const float* __restrict__ Wq, const float* __restrict__ Wk,
    const float* __restrict__ Wv, const float* __restrict__ Wo,
    const float* __restrict__ W1, const float* __restrict__ W2,
    unsigned short* __restrict__ xb,
    unsigned short* __restrict__ wqT, unsigned short* __restrict__ wkT,
    unsigned short* __restrict__ wvT, unsigned short* __restrict__ woT,
    unsigned short* __restrict__ w1T, unsigned short* __restrict__ w2T) {
  int b = blockIdx.x, t = threadIdx.x;
  if (b < 1024) {
    int i8 = (b * 256 + t) * 8;
    const float4* p = reinterpret_cast<const float4*>(x + i8);
    float4 v0 = p[0], v1 = p[1];
    short8 o;
    o[0] = (short)f2b(v0.x); o[1] = (short)f2b(v0.y);
    o[2] = (short)f2b(v0.z); o[3] = (short)f2b(v0.w);
    o[4] = (short)f2b(v1.x); o[5] = (short)f2b(v1.y);
    o[6] = (short)f2b(v1.z); o[7] = (short)f2b(v1.w);
    *reinterpret_cast<short8*>(xb + i8) = o;
    return;
  }
  const float* src; unsigned short* dst; int K, N, base;
  if      (b < 1088) { src = Wq; dst = wqT; K = 128; N = 128; base = 1024; }
  else if (b < 1152) { src = Wk; dst = wkT; K = 128; N = 128; base = 1088; }
  else if (b < 1216) { src = Wv; dst = wvT; K = 128; N = 128; base = 1152; }
  else if (b < 1280) { src = Wo; dst = woT; K = 128; N = 128; base = 1216; }
  else if (b < 1536) { src = W1; dst = w1T; K = 128; N = 512; base = 1280; }
  else               { src = W2; dst = w2T; K = 512; N = 128; base = 1536; }
  int idx = (b - base) * 256 + t;
  int k = idx / N, n = idx - k * N;
  dst[n * K + k] = f2b(src[idx]);
}

// ---------------- GEMM tile cores ----------------
// A: [M][KDIM] bf16 row-major; BT: [N][KDIM] bf16 row-major (B transposed).
// SWAP=false: acc[c] holds C rows t=row0+4g+r, col n=n0+16c+ln.
// SWAP=true : acc[c] holds C^T: token t=row0+ln, cols n=n0+16c+4g+r.
template <int KDIM, bool SWAP>
DEV void gemm_tile(const unsigned short* __restrict__ A,
                   const unsigned short* __restrict__ BT,
                   int row0, int n0, int ln, int g, f32x4 acc[8]) {
#pragma unroll
  for (int ks = 0; ks < KDIM; ks += 32) {
    short8 a = *reinterpret_cast<const short8*>(A + (size_t)(row0 + ln) * KDIM + ks + 8 * g);
#pragma unroll
    for (int c = 0; c < 8; ++c) {
      short8 b = *reinterpret_cast<const short8*>(BT + (size_t)(n0 + c * 16 + ln) * KDIM + ks + 8 * g);
      if constexpr (SWAP)
        acc[c] = __builtin_amdgcn_mfma_f32_16x16x32_bf16(b, a, acc[c], 0, 0, 0);
      else
        acc[c] = __builtin_amdgcn_mfma_f32_16x16x32_bf16(a, b, acc[c], 0, 0, 0);
    }
  }
}

// K-sliced swapped GEMM: k0..k0+KLEN of a length-LDA/LDB K axis, N=128.
template <int LDA, int LDB, int KLEN>
DEV void gemm_tileK(const unsigned short* __restrict__ A,
                    const unsigned short* __restrict__ BT,
                    int row0, int k0, int ln, int g, f32x4 acc[8]) {
#pragma unroll
  for (int ks = 0; ks < KLEN; ks += 32) {
    short8 a = *reinterpret_cast<const short8*>(A + (size_t)(row0 + ln) * LDA + k0 + ks + 8 * g);
#pragma unroll
    for (int c = 0; c < 8; ++c) {
      short8 b = *reinterpret_cast<const short8*>(BT + (size_t)(c * 16 + ln) * LDB + k0 + ks + 8 * g);
      acc[c] = __builtin_amdgcn_mfma_f32_16x16x32_bf16(b, a, acc[c], 0, 0, 0);
    }
  }
}

// ---------------- QKV projection ----------------
__global__ __launch_bounds__(256) void qkv_kernel(
    const unsigned short* __restrict__ xb,
    const unsigned short* __restrict__ wqT, const unsigned short* __restrict__ wkT,
    const unsigned short* __restrict__ wvT,
    const float* __restrict__ bq, const float* __restrict__ bk, const float* __restrict__ bv,
    unsigned short* __restrict__ q, unsigned short* __restrict__ k,
    unsigned short* __restrict__ vT) {
  int w = threadIdx.x >> 6, lane = threadIdx.x & 63;
  int g = lane >> 4, ln = lane & 15;
  int z = blockIdx.y;
  int row0 = blockIdx.x * 64 + w * 16;
  const unsigned short* BT = (z == 0) ? wqT : (z == 1) ? wkT : wvT;
  const float* bias = (z == 0) ? bq : (z == 1) ? bk : bv;
  f32x4 acc[8];
#pragma unroll
  for (int c = 0; c < 8; ++c) acc[c] = f32x4{0.f, 0.f, 0.f, 0.f};
  if (z == 2) {
    gemm_tile<128, false>(xb, BT, row0, 0, ln, g, acc);
#pragma unroll
    for (int c = 0; c < 8; ++c) {
      int n = c * 16 + ln;
      int h = n >> 5, dh = n & 31;
      float bi = bias[n];
      int t0 = row0 + 4 * g;
      int b_ = t0 >> 11, s0 = t0 & 2047;
      size_t off = ((size_t)(b_ * Hh + h) * DH + dh) * S + s0;
      uint2 st;
      st.x = pack2(acc[c][0] + bi, acc[c][1] + bi);
      st.y = pack2(acc[c][2] + bi, acc[c][3] + bi);
      *reinterpret_cast<uint2*>(vT + off) = st;
    }
  } else {
    gemm_tile<128, true>(xb, BT, row0, 0, ln, g, acc);
    unsigned short* dst = (z == 0) ? q : k;
    int t = row0 + ln;
    int b_ = t >> 11, s = t & 2047;
#pragma unroll
    for (int c = 0; c < 8; ++c) {
      int nc = c * 16 + 4 * g;
      int h = nc >> 5, dh0 = nc & 31;
      f32x4 bi = *reinterpret_cast<const f32x4*>(bias + nc);
      float f = 1.0f;
      if (z == 0) f = (dh0 < 8) ? -QSCALE : QSCALE;
      float v0 = (acc[c][0] + bi[0]) * f, v1 = (acc[c][1] + bi[1]) * f;
      float v2 = (acc[c][2] + bi[2]) * f, v3 = (acc[c][3] + bi[3]) * f;
      uint2 st;
      st.x = pack2(v0, v1);
      st.y = pack2(v2, v3);
      *reinterpret_cast<uint2*>(dst + ((size_t)(b_ * Hh + h) * S + s) * DH + dh0) = st;
    }
  }
}

// ---------------- flash attention ----------------
// grid: (32 q-tiles of 64, 32 bh). block: 512 thr = 8 waves.
// wave w: w_q = w>>2 (32 q rows), w_kv = w&3 (512-kv quarter). No inner
// barriers (P wave-private); 4-way partial merge at the end via LDS overlay.
__global__ __launch_bounds__(512, 8) void attn_kernel(
    const unsigned short* __restrict__ q, const unsigned short* __restrict__ k,
    const unsigned short* __restrict__ vT, unsigned short* __restrict__ ao) {
  __shared__ float smem_f[9216];  // 36864 B: P_lds during loop, mbuf after
  unsigned short (*P_lds)[32][72] = reinterpret_cast<unsigned short(*)[32][72]>(smem_f);
  int w = threadIdx.x >> 6, lane = threadIdx.x & 63;
  int g = lane >> 4, ln = lane & 15;
  int w_q = w >> 2, w_kv = w & 3;
  int bh = blockIdx.y;
  int qbase = blockIdx.x * 64 + w_q * 32;
  const unsigned short* qp = q + (size_t)bh * S * DH;
  const unsigned short* kp = k + (size_t)bh * S * DH;
  const unsigned short* vp = vT + (size_t)bh * DH * S;

  short8 qfr[2];
#pragma unroll
  for (int qf = 0; qf < 2; ++qf)
    qfr[qf] = *reinterpret_cast<const short8*>(qp + (size_t)(qbase + qf * 16 + ln) * DH + 8 * g);

  float m[2] = {0.f, 0.f};
  float lsum[2] = {0.f, 0.f};
  int mz[2] = {1, 1};  // m[qf]==0 fast-path flag (wave-uniform)
  f32x4 acc[2][2];     // [vf][qf] O^T fragments
#pragma unroll
  for (int a = 0; a < 2; ++a)
#pragma unroll
    for (int b = 0; b < 2; ++b) acc[a][b] = f32x4{0.f, 0.f, 0.f, 0.f};

  for (int kt = 0; kt < 8; ++kt) {
    int kv0 = w_kv * 512 + kt * 64;
    short8 kf[4];
#pragma unroll
    for (int c = 0; c < 4; ++c)
      kf[c] = *reinterpret_cast<const short8*>(kp + (size_t)(kv0 + c * 16 + ln) * DH + 8 * g);
    f32x4 sst[4][2];
#pragma unroll
    for (int c = 0; c < 4; ++c)
#pragma unroll
      for (int qf = 0; qf < 2; ++qf)
        sst[c][qf] = __builtin_amdgcn_mfma_f32_16x16x32_bf16(kf[c], qfr[qf],
                                                             f32x4{0.f, 0.f, 0.f, 0.f}, 0, 0, 0);
#pragma unroll
    for (int qf = 0; qf < 2; ++qf) {
      float partial = 0.f;
      if (__builtin_amdgcn_readfirstlane(mz[qf])) {
#pragma unroll
        for (int c = 0; c < 4; ++c)
#pragma unroll
          for (int r = 0; r < 4; ++r) {
            float p = exp2f(sst[c][qf][r]);
            sst[c][qf][r] = p;
            partial += p;
          }
      } else {
#pragma unroll
        for (int c = 0; c < 4; ++c)
#pragma unroll
          for (int r = 0; r < 4; ++r) {
            float p = exp2f(sst[c][qf][r] - m[qf]);
            sst[c][qf][r] = p;
            partial += p;
          }
      }
      // overflow guard (rare): recover max from p, rescale in-register.
      if (!__all(partial <= 16777216.0f)) {
        float pm = sst[0][qf][0];
#pragma unroll
        for (int c = 0; c < 4; ++c)
#pragma unroll
          for (int r = 0; r < 4; ++r) pm = fmaxf(pm, sst[c][qf][r]);
        pm = fmaxf(pm, __shfl_xor(pm, 16));
        pm = fmaxf(pm, __shfl_xor(pm, 32));
        float mnew = log2f(pm) + m[qf];
        float cs = exp2f(m[qf] - mnew);
        m[qf] = mnew;
        mz[qf] = 0;
        lsum[qf] *= cs;
        partial *= cs;
#pragma unroll
        for (int c = 0; c < 4; ++c)
#pragma unroll
          for (int r = 0; r < 4; ++r) sst[c][qf][r] *= cs;
#pragma unroll
        for (int vf = 0; vf < 2; ++vf)
#pragma unroll
          for (int r = 0; r < 4; ++r) acc[vf][qf][r] *= cs;
      }
      partial += __shfl_xor(partial, 16);
      partial += __shfl_xor(partial, 32);
      lsum[qf] += partial;
#pragma unroll
      for (int c = 0; c < 4; ++c) {
        uint2 st;
        st.x = pack2(sst[c][qf][0], sst[c][qf][1]);
        st.y = pack2(sst[c][qf][2], sst[c][qf][3]);
        *reinterpret_cast<uint2*>(&P_lds[w][qf * 16 + ln][c * 16 + 4 * g]) = st;
      }
    }
#pragma unroll
    for (int hv = 0; hv < 2; ++hv) {
      short8 vfr[2];
#pragma unroll
      for (int vf = 0; vf < 2; ++vf)
        vfr[vf] = *reinterpret_cast<const short8*>(vp + (size_t)(vf * 16 + ln) * S + kv0 + hv * 32 + 8 * g);
#pragma unroll
      for (int qf = 0; qf < 2; ++qf) {
        short8 pf = *reinterpret_cast<const short8*>(&P_lds[w][qf * 16 + ln][hv * 32 + 8 * g]);
#pragma unroll
        for (int vf = 0; vf < 2; ++vf)
          acc[vf][qf] = __builtin_amdgcn_mfma_f32_16x16x32_bf16(vfr[vf], pf, acc[vf][qf], 0, 0, 0);
      }
    }
  }
  // ---- merge 4 kv-partials ----
  __syncthreads();  // all P reads done; smem becomes mbuf[w_q][slot][lane][20]
  if (w_kv) {
    float* mb = smem_f + ((w_q * 3 + (w_kv - 1)) * 64 + lane) * 20;
    mb[0] = m[0]; mb[1] = m[1]; mb[2] = lsum[0]; mb[3] = lsum[1];
#pragma unroll
    for (int vf = 0; vf < 2; ++vf)
#pragma unroll
      for (int qf = 0; qf < 2; ++qf)
#pragma unroll
        for (int r = 0; r < 4; ++r) mb[4 + (vf * 2 + qf) * 4 + r] = acc[vf][qf][r];
  }
  __syncthreads();
  if (w_kv == 0) {
    const float* mb0 = smem_f + ((w_q * 3 + 0) * 64 + lane) * 20;
    const float* mb1 = smem_f + ((w_q * 3 + 1) * 64 + lane) * 20;
    const float* mb2 = smem_f + ((w_q * 3 + 2) * 64 + lane) * 20;
    int b_ = bh >> 2, h = bh & 3;
#pragma unroll
    for (int qf = 0; qf < 2; ++qf) {
      float mt = fmaxf(fmaxf(m[qf], mb0[qf]), fmaxf(mb1[qf], mb2[qf]));
      float e0 = exp2f(m[qf] - mt);
      float e1 = exp2f(mb0[qf] - mt);
      float e2 = exp2f(mb1[qf] - mt);
      float e3 = exp2f(mb2[qf] - mt);
      float lt = lsum[qf] * e0 + mb0[2 + qf] * e1 + mb1[2 + qf] * e2 + mb2[2 + qf] * e3;
      float inv = 1.0f / lt;
      int qrow = qbase + qf * 16 + ln;
#pragma unroll
      for (int vf = 0; vf < 2; ++vf) {
        int dh0 = vf * 16 + 4 * g;
        int ai = 4 + (vf * 2 + qf) * 4;
        float o[4];
#pragma unroll
        for (int r = 0; r < 4; ++r)
          o[r] = (acc[vf][qf][r] * e0 + mb0[ai + r] * e1 + mb1[ai + r] * e2 + mb2[ai + r] * e3) * inv;
        uint2 st;
        st.x = pack2(o[0], o[1]);
        st.y = pack2(o[2], o[3]);
        *reinterpret_cast<uint2*>(ao + ((size_t)(b_ * S + qrow)) * D + h * DH + dh0) = st;
      }
    }
  }
}

// ---------------- out-proj + residual + Minkowski LN (K-split 2x64) ----------------
__global__ __launch_bounds__(512) void projln_kernel(
    const unsigned short* __restrict__ ao, const unsigned short* __restrict__ woT,
    const float* __restrict__ bo, const float* __restrict__ x,
    const float* __restrict__ g1t, const float* __restrict__ b1t,
    const float* __restrict__ g1s, const float* __restrict__ b1s,
    float* __restrict__ x1, unsigned short* __restrict__ x1b) {
  __shared__ float part[4][16][132];
  int w = threadIdx.x >> 6, lane = threadIdx.x & 63;
  int g = lane >> 4, ln = lane & 15;
  int wm = w >> 1, wk = w & 1;
  int row0 = blockIdx.x * 64 + wm * 16;
  f32x4 acc[8];
#pragma unroll
  for (int c = 0; c < 8; ++c) acc[c] = f32x4{0.f, 0.f, 0.f, 0.f};
  gemm_tileK<128, 128, 64>(ao, woT, row0, wk * 64, ln, g, acc);
  if (wk == 1) {
#pragma unroll
    for (int c = 0; c < 8; ++c)
      *reinterpret_cast<f32x4*>(&part[wm][ln][c * 16 + 4 * g]) = acc[c];
  }
  __syncthreads();
  if (wk == 1) return;
  int t = row0 + ln;
  float rv[8][4];
#pragma unroll
  for (int c = 0; c < 8; ++c) {
    int nc = c * 16 + 4 * g;
    f32x4 pp = *reinterpret_cast<const f32x4*>(&part[wm][ln][nc]);
    f32x4 bi = *reinterpret_cast<const f32x4*>(bo + nc);
    f32x4 xr = *reinterpret_cast<const f32x4*>(x + (size_t)t * D + nc);
#pragma unroll
    for (int r = 0; r < 4; ++r) rv[c][r] = acc[c][r] + pp[r] + bi[r] + xr[r];
  }
  float st = 0.f, ss = 0.f;
#pragma unroll
  for (int c = 0; c < 2; ++c)
#pragma unroll
    for (int r = 0; r < 4; ++r) st += rv[c][r];
#pragma unroll
  for (int c = 2; c < 8; ++c)
#pragma unroll
    for (int r = 0; r < 4; ++r) ss += rv[c][r];
  st += __shfl_xor(st, 16); st += __shfl_xor(st, 32);
  ss += __shfl_xor(ss, 16); ss += __shfl_xor(ss, 32);
  float mut = st * (1.f / 32.f), mus = ss * (1.f / 96.f);
  float vt = 0.f, vs = 0.f;
#pragma unroll
  for (int c = 0; c < 2; ++c)
#pragma unroll
    for (int r = 0; r < 4; ++r) { float d = rv[c][r] - mut; vt += d * d; }
#pragma unroll
  for (int c = 2; c < 8; ++c)
#pragma unroll
    for (int r = 0; r < 4; ++r) { float d = rv[c][r] - mus; vs += d * d; }
  vt += __shfl_xor(vt, 16); vt += __shfl_xor(vt, 32);
  vs += __shfl_xor(vs, 16); vs += __shfl_xor(vs, 32);
  float rst = rsqrtf(vt * (1.f / 32.f) + EPSV);
  float rss = rsqrtf(vs * (1.f / 96.f) + EPSV);
#pragma unroll
  for (int c = 0; c < 8; ++c) {
    int nc = c * 16 + 4 * g;
    f32x4 ga, bb;
    if (c < 2) {
      ga = *reinterpret_cast<const f32x4*>(g1t + nc);
      bb = *reinterpret_cast<const f32x4*>(b1t + nc);
    } else {
      ga = *reinterpret_cast<const f32x4*>(g1s + nc - 32);
      bb = *reinterpret_cast<const f32x4*>(b1s + nc - 32);
    }
    f32x4 o4;
#pragma unroll
    for (int r = 0; r < 4; ++r)
      o4[r] = (c < 2) ? (rv[c][r] - mut) * rst * ga[r] + bb[r]
                      : (rv[c][r] - mus) * rss * ga[r] + bb[r];
    *reinterpret_cast<f32x4*>(x1 + (size_t)t * D + nc) = o4;
    uint2 sb;
    sb.x = pack2(o4[0], o4[1]);
    sb.y = pack2(o4[2], o4[3]);
    *reinterpret_cast<uint2*>(x1b + (size_t)t * D + nc) = sb;
  }
}

// ---------------- FFN1 + exact GELU ----------------
__global__ __launch_bounds__(256) void ffn1_kernel(
    const unsigned short* __restrict__ x1b, const unsigned short* __restrict__ w1T,
    const float* __restrict__ bf1, unsigned short* __restrict__ h) {
  int w = threadIdx.x >> 6, lane = threadIdx.x & 63;
  int g = lane >> 4, ln = lane & 15;
  int row0 = blockIdx.x * 64 + w * 16;
  int n0 = blockIdx.y * 128;
  f32x4 acc[8];
#pragma unroll
  for (int c = 0; c < 8; ++c) acc[c] = f32x4{0.f, 0.f, 0.f, 0.f};
  gemm_tile<128, true>(x1b, w1T, row0, n0, ln, g, acc);
  int t = row0 + ln;
#pragma unroll
  for (int c = 0; c < 8; ++c) {
    int nc = n0 + c * 16 + 4 * g;
    f32x4 bi = *reinterpret_cast<const f32x4*>(bf1 + nc);
    float ge[4];
#pragma unroll
    for (int r = 0; r < 4; ++r) {
      float v = acc[c][r] + bi[r];
      ge[r] = 0.5f * v * (1.0f + erff(v * 0.70710678118654752f));
    }
    uint2 stv;
    stv.x = pack2(ge[0], ge[1]);
    stv.y = pack2(ge[2], ge[3]);
    *reinterpret_cast<uint2*>(h + (size_t)t * 512 + nc) = stv;
  }
}

// ---------------- FFN2 + residual + Minkowski LN (K-split 2x256) ----------------
__global__ __launch_bounds__(512) void ffn2_kernel(
    const unsigned short* __restrict__ h, const unsigned short* __restrict__ w2T,
    const float* __restrict__ bf2, const float* __restrict__ x1,
    const float* __restrict__ g2t, const float* __restrict__ b2t,
    const float* __restrict__ g2s, const float* __restrict__ b2s,
    float* __restrict__ out) {
  __shared__ float part[4][16][132];
  int w = threadIdx.x >> 6, lane = threadIdx.x & 63;
  int g = lane >> 4, ln = lane & 15;
  int wm = w >> 1, wk = w & 1;
  int row0 = blockIdx.x * 64 + wm * 16;
  f32x4 acc[8];
#pragma unroll
  for (int c = 0; c < 8; ++c) acc[c] = f32x4{0.f, 0.f, 0.f, 0.f};
  gemm_tileK<512, 512, 256>(h, w2T, row0, wk * 256, ln, g, acc);
  if (wk == 1) {
#pragma unroll
    for (int c = 0; c < 8; ++c)
      *reinterpret_cast<f32x4*>(&part[wm][ln][c * 16 + 4 * g]) = acc[c];
  }
  __syncthreads();
  if (wk == 1) return;
  int t = row0 + ln;
  float rv[8][4];
#pragma unroll
  for (int c = 0; c < 8; ++c) {
    int nc = c * 16 + 4 * g;
    f32x4 pp = *reinterpret_cast<const f32x4*>(&part[wm][ln][nc]);
    f32x4 bi = *reinterpret_cast<const f32x4*>(bf2 + nc);
    f32x4 xr = *reinterpret_cast<const f32x4*>(x1 + (size_t)t * D + nc);
#pragma unroll
    for (int r = 0; r < 4; ++r) rv[c][r] = acc[c][r] + pp[r] + bi[r] + xr[r];
  }
  float st = 0.f, ss = 0.f;
#pragma unroll
  for (int c = 0; c < 2; ++c)
#pragma unroll
    for (int r = 0; r < 4; ++r) st += rv[c][r];
#pragma unroll
  for (int c = 2; c < 8; ++c)
#pragma unroll
    for (int r = 0; r < 4; ++r) ss += rv[c][r];
  st += __shfl_xor(st, 16); st += __shfl_xor(st, 32);
  ss += __shfl_xor(ss, 16); ss += __shfl_xor(ss, 32);
  float mut = st * (1.f / 32.f), mus = ss * (1.f / 96.f);
  float vt = 0.f, vs = 0.f;
#pragma unroll
  for (int c = 0; c < 2; ++c)
#pragma unroll
    for (int r = 0; r < 4; ++r) { float d = rv[c][r] - mut; vt += d * d; }
#pragma unroll
  for (int c = 2; c < 8; ++c)
#pragma unroll
    for (int r = 0; r < 4; ++r) { float d = rv[c][r] - mus; vs += d * d; }
  vt += __shfl_xor(vt, 16); vt += __shfl_xor(vt, 32);
  vs += __shfl_xor(vs, 16); vs += __shfl_xor(vs, 32);
  float rst = rsqrtf(vt * (1.f / 32.f) + EPSV);
  float rss = rsqrtf(vs * (1.f / 96.f) + EPSV);
#pragma unroll
  for (int c = 0; c < 8; ++c) {
    int nc = c * 16 + 4 * g;
    f32x4 ga, bb;
    if (c < 2) {
      ga = *reinterpret_cast<const f32x4*>(g2t + nc);
      bb = *reinterpret_cast<const f32x4*>(b2t + nc);
    } else {
      ga = *reinterpret_cast<const f32x4*>(g2s + nc - 32);
      bb = *reinterpret_cast<const f32x4*>(b2s + nc - 32);
    }
    f32x4 o4;
#pragma unroll
    for (int r = 0; r < 4; ++r)
      o4[r] = (c < 2) ? (rv[c][r] - mut) * rst * ga[r] + bb[r]
                      : (rv[c][r] - mus) * rss * ga[r] + bb[r];
    *reinterpret_cast<f32x4*>(out + (size_t)t * D + nc) = o4;
  }
}

extern "C" void kernel_launch(void* const* d_in, const int* in_sizes, int n_in,
                              void* d_out, int out_size, void* d_ws, size_t ws_size,
                              hipStream_t stream) {
  (void)in_sizes; (void)n_in; (void)out_size; (void)ws_size;
  const float* x   = (const float*)d_in[0];
  const float* Wq  = (const float*)d_in[1];
  const float* bq  = (const float*)d_in[2];
  const float* Wk  = (const float*)d_in[3];
  const float* bk  = (const float*)d_in[4];
  const float* Wv  = (const float*)d_in[5];
  const float* bv  = (const float*)d_in[6];
  const float* Wo  = (const float*)d_in[7];
  const float* bo  = (const float*)d_in[8];
  const float* g1t = (const float*)d_in[9];
  const float* b1t = (const float*)d_in[10];
  const float* g1s = (const float*)d_in[11];
  const float* b1s = (const float*)d_in[12];
  const float* W1  = (const float*)d_in[13];
  const float* bf1 = (const float*)d_in[14];
  const float* W2  = (const float*)d_in[15];
  const float* bf2 = (const float*)d_in[16];
  const float* g2t = (const float*)d_in[17];
  const float* b2t = (const float*)d_in[18];
  const float* g2s = (const float*)d_in[19];
  const float* b2s = (const float*)d_in[20];

  char* ws = (char*)d_ws;
  unsigned short* xb  = (unsigned short*)(ws);                 // 16384x128 bf16
  unsigned short* wqT = (unsigned short*)(ws + 4194304);
  unsigned short* wkT = wqT + 16384;
  unsigned short* wvT = wkT + 16384;
  unsigned short* woT = wvT + 16384;
  unsigned short* w1T = woT + 16384;   // [512][128]
  unsigned short* w2T = w1T + 65536;   // [128][512]
  unsigned short* qb  = w2T + 65536;   // [8][4][2048][32]
  unsigned short* kb  = qb + 2097152;
  unsigned short* vT  = kb + 2097152;  // [8][4][32][2048]
  unsigned short* ao  = vT + 2097152;  // [16384][128]
  float* x1           = (float*)(ao + 2097152);      // [16384][128] f32
  unsigned short* x1b = (unsigned short*)(x1 + 2097152);
  unsigned short* hbf = x1b + 2097152; // [16384][512]
  float* outp = (float*)d_out;

  prep_kernel<<<1792, 256, 0, stream>>>(x, Wq, Wk, Wv, Wo, W1, W2,
                                        xb, wqT, wkT, wvT, woT, w1T, w2T);
  qkv_kernel<<<dim3(256, 3), 256, 0, stream>>>(xb, wqT, wkT, wvT, bq, bk, bv, qb, kb, vT);
  attn_kernel<<<dim3(32, 32), 512, 0, stream>>>(qb, kb, vT, ao);
  projln_kernel<<<256, 512, 0, stream>>>(ao, woT, bo, x, g1t, b1t, g1s, b1s, x1, x1b);
  ffn1_kernel<<<dim3(256, 4), 256, 0, stream>>>(x1b, w1T, bf1, hbf);
  ffn2_kernel<<<256, 512, 0, stream>>>(hbf, w2T, bf2, x1, g2t, b2t, g2s, b2s, outp);
}

// Round 4
// 137.085 us; speedup vs baseline: 1.4662x; 1.4662x over previous
//
#include <hip/hip_runtime.h>
#include <hip/hip_bf16.h>

#define DEV __device__ __forceinline__

typedef __attribute__((ext_vector_type(8))) short short8;
typedef __attribute__((ext_vector_type(4))) float f32x4;

constexpr int D   = 128;
constexpr int S   = 2048;
constexpr int Hh  = 4;
constexpr int DH  = 32;
// 1/sqrt(32) * log2(e): QK^T logits land directly in exp2 domain.
constexpr float QSCALE = 0.17677669529663687f * 1.4426950408889634f;
constexpr float EPSV = 1e-5f;

DEV unsigned short f2b(float f) {
  __hip_bfloat16 h = __float2bfloat16(f);
  return *reinterpret_cast<unsigned short*>(&h);
}
DEV unsigned pack2(float a, float b) {
  return (unsigned)f2b(a) | ((unsigned)f2b(b) << 16);
}

// ---------------- prep: x -> bf16, weights -> bf16 transposed ----------------
__global__ __launch_bounds__(256) void prep_kernel(
    const float* __restrict__ x,
    const float* __restrict__ Wq, const float* __restrict__ Wk,
    const float* __restrict__ Wv, const float* __restrict__ Wo,
    const float* __restrict__ W1, const float* __restrict__ W2,
    unsigned short* __restrict__ xb,
    unsigned short* __restrict__ wqT, unsigned short* __restrict__ wkT,
    unsigned short* __restrict__ wvT, unsigned short* __restrict__ woT,
    unsigned short* __restrict__ w1T, unsigned short* __restrict__ w2T) {
  int b = blockIdx.x, t = threadIdx.x;
  if (b < 1024) {
    int i8 = (b * 256 + t) * 8;
    const float4* p = reinterpret_cast<const float4*>(x + i8);
    float4 v0 = p[0], v1 = p[1];
    short8 o;
    o[0] = (short)f2b(v0.x); o[1] = (short)f2b(v0.y);
    o[2] = (short)f2b(v0.z); o[3] = (short)f2b(v0.w);
    o[4] = (short)f2b(v1.x); o[5] = (short)f2b(v1.y);
    o[6] = (short)f2b(v1.z); o[7] = (short)f2b(v1.w);
    *reinterpret_cast<short8*>(xb + i8) = o;
    return;
  }
  const float* src; unsigned short* dst; int K, N, base;
  if      (b < 1088) { src = Wq; dst = wqT; K = 128; N = 128; base = 1024; }
  else if (b < 1152) { src = Wk; dst = wkT; K = 128; N = 128; base = 1088; }
  else if (b < 1216) { src = Wv; dst = wvT; K = 128; N = 128; base = 1152; }
  else if (b < 1280) { src = Wo; dst = woT; K = 128; N = 128; base = 1216; }
  else if (b < 1536) { src = W1; dst = w1T; K = 128; N = 512; base = 1280; }
  else               { src = W2; dst = w2T; K = 512; N = 128; base = 1536; }
  int idx = (b - base) * 256 + t;
  int k = idx / N, n = idx - k * N;
  dst[n * K + k] = f2b(src[idx]);
}

// ---------------- GEMM tile cores ----------------
// A: [M][KDIM] bf16 row-major; BT: [N][KDIM] bf16 row-major (B transposed).
// SWAP=false: acc[c] holds C rows t=row0+4g+r, col n=n0+16c+ln.
// SWAP=true : acc[c] holds C^T: token t=row0+ln, cols n=n0+16c+4g+r.
template <int KDIM, bool SWAP>
DEV void gemm_tile(const unsigned short* __restrict__ A,
                   const unsigned short* __restrict__ BT,
                   int row0, int n0, int ln, int g, f32x4 acc[8]) {
#pragma unroll
  for (int ks = 0; ks < KDIM; ks += 32) {
    short8 a = *reinterpret_cast<const short8*>(A + (size_t)(row0 + ln) * KDIM + ks + 8 * g);
#pragma unroll
    for (int c = 0; c < 8; ++c) {
      short8 b = *reinterpret_cast<const short8*>(BT + (size_t)(n0 + c * 16 + ln) * KDIM + ks + 8 * g);
      if constexpr (SWAP)
        acc[c] = __builtin_amdgcn_mfma_f32_16x16x32_bf16(b, a, acc[c], 0, 0, 0);
      else
        acc[c] = __builtin_amdgcn_mfma_f32_16x16x32_bf16(a, b, acc[c], 0, 0, 0);
    }
  }
}

// K-sliced swapped GEMM: k0..k0+KLEN of a length-LDA/LDB K axis, N=128.
template <int LDA, int LDB, int KLEN>
DEV void gemm_tileK(const unsigned short* __restrict__ A,
                    const unsigned short* __restrict__ BT,
                    int row0, int k0, int ln, int g, f32x4 acc[8]) {
#pragma unroll
  for (int ks = 0; ks < KLEN; ks += 32) {
    short8 a = *reinterpret_cast<const short8*>(A + (size_t)(row0 + ln) * LDA + k0 + ks + 8 * g);
#pragma unroll
    for (int c = 0; c < 8; ++c) {
      short8 b = *reinterpret_cast<const short8*>(BT + (size_t)(c * 16 + ln) * LDB + k0 + ks + 8 * g);
      acc[c] = __builtin_amdgcn_mfma_f32_16x16x32_bf16(b, a, acc[c], 0, 0, 0);
    }
  }
}

// ---------------- QKV projection ----------------
__global__ __launch_bounds__(256) void qkv_kernel(
    const unsigned short* __restrict__ xb,
    const unsigned short* __restrict__ wqT, const unsigned short* __restrict__ wkT,
    const unsigned short* __restrict__ wvT,
    const float* __restrict__ bq, const float* __restrict__ bk, const float* __restrict__ bv,
    unsigned short* __restrict__ q, unsigned short* __restrict__ k,
    unsigned short* __restrict__ vT) {
  int w = threadIdx.x >> 6, lane = threadIdx.x & 63;
  int g = lane >> 4, ln = lane & 15;
  int z = blockIdx.y;
  int row0 = blockIdx.x * 64 + w * 16;
  const unsigned short* BT = (z == 0) ? wqT : (z == 1) ? wkT : wvT;
  const float* bias = (z == 0) ? bq : (z == 1) ? bk : bv;
  f32x4 acc[8];
#pragma unroll
  for (int c = 0; c < 8; ++c) acc[c] = f32x4{0.f, 0.f, 0.f, 0.f};
  if (z == 2) {
    gemm_tile<128, false>(xb, BT, row0, 0, ln, g, acc);
#pragma unroll
    for (int c = 0; c < 8; ++c) {
      int n = c * 16 + ln;
      int h = n >> 5, dh = n & 31;
      float bi = bias[n];
      int t0 = row0 + 4 * g;
      int b_ = t0 >> 11, s0 = t0 & 2047;
      size_t off = ((size_t)(b_ * Hh + h) * DH + dh) * S + s0;
      uint2 st;
      st.x = pack2(acc[c][0] + bi, acc[c][1] + bi);
      st.y = pack2(acc[c][2] + bi, acc[c][3] + bi);
      *reinterpret_cast<uint2*>(vT + off) = st;
    }
  } else {
    gemm_tile<128, true>(xb, BT, row0, 0, ln, g, acc);
    unsigned short* dst = (z == 0) ? q : k;
    int t = row0 + ln;
    int b_ = t >> 11, s = t & 2047;
#pragma unroll
    for (int c = 0; c < 8; ++c) {
      int nc = c * 16 + 4 * g;
      int h = nc >> 5, dh0 = nc & 31;
      f32x4 bi = *reinterpret_cast<const f32x4*>(bias + nc);
      float f = 1.0f;
      if (z == 0) f = (dh0 < 8) ? -QSCALE : QSCALE;
      float v0 = (acc[c][0] + bi[0]) * f, v1 = (acc[c][1] + bi[1]) * f;
      float v2 = (acc[c][2] + bi[2]) * f, v3 = (acc[c][3] + bi[3]) * f;
      uint2 st;
      st.x = pack2(v0, v1);
      st.y = pack2(v2, v3);
      *reinterpret_cast<uint2*>(dst + ((size_t)(b_ * Hh + h) * S + s) * DH + dh0) = st;
    }
  }
}

// ---------------- flash attention ----------------
// grid: (32 q-tiles of 64, 32 bh). block: 512 thr = 8 waves.
// wave w: w_q = w>>2 (32 q rows), w_kv = w&3 (512-kv quarter). No inner
// barriers (P wave-private); 4-way partial merge at the end via LDS overlay.
// NOTE: (512,4) not (512,8) — 8 waves/EU caps VGPR at 64 and the ~70-reg
// working set spills to scratch (round-3 post-mortem: 270 MB WRITE_SIZE).
__global__ __launch_bounds__(512, 4) void attn_kernel(
    const unsigned short* __restrict__ q, const unsigned short* __restrict__ k,
    const unsigned short* __restrict__ vT, unsigned short* __restrict__ ao) {
  __shared__ float smem_f[9216];  // 36864 B: P_lds during loop, mbuf after
  unsigned short (*P_lds)[32][72] = reinterpret_cast<unsigned short(*)[32][72]>(smem_f);
  int w = threadIdx.x >> 6, lane = threadIdx.x & 63;
  int g = lane >> 4, ln = lane & 15;
  int w_q = w >> 2, w_kv = w & 3;
  int bh = blockIdx.y;
  int qbase = blockIdx.x * 64 + w_q * 32;
  const unsigned short* qp = q + (size_t)bh * S * DH;
  const unsigned short* kp = k + (size_t)bh * S * DH;
  const unsigned short* vp = vT + (size_t)bh * DH * S;

  short8 qfr[2];
#pragma unroll
  for (int qf = 0; qf < 2; ++qf)
    qfr[qf] = *reinterpret_cast<const short8*>(qp + (size_t)(qbase + qf * 16 + ln) * DH + 8 * g);

  float m[2] = {0.f, 0.f};
  float lsum[2] = {0.f, 0.f};
  int mz[2] = {1, 1};  // m[qf]==0 fast-path flag (wave-uniform)
  f32x4 acc[2][2];     // [vf][qf] O^T fragments
#pragma unroll
  for (int a = 0; a < 2; ++a)
#pragma unroll
    for (int b = 0; b < 2; ++b) acc[a][b] = f32x4{0.f, 0.f, 0.f, 0.f};

  for (int kt = 0; kt < 8; ++kt) {
    int kv0 = w_kv * 512 + kt * 64;
    short8 kf[4];
#pragma unroll
    for (int c = 0; c < 4; ++c)
      kf[c] = *reinterpret_cast<const short8*>(kp + (size_t)(kv0 + c * 16 + ln) * DH + 8 * g);
    f32x4 sst[4][2];
#pragma unroll
    for (int c = 0; c < 4; ++c)
#pragma unroll
      for (int qf = 0; qf < 2; ++qf)
        sst[c][qf] = __builtin_amdgcn_mfma_f32_16x16x32_bf16(kf[c], qfr[qf],
                                                             f32x4{0.f, 0.f, 0.f, 0.f}, 0, 0, 0);
#pragma unroll
    for (int qf = 0; qf < 2; ++qf) {
      float partial = 0.f;
      if (__builtin_amdgcn_readfirstlane(mz[qf])) {
#pragma unroll
        for (int c = 0; c < 4; ++c)
#pragma unroll
          for (int r = 0; r < 4; ++r) {
            float p = exp2f(sst[c][qf][r]);
            sst[c][qf][r] = p;
            partial += p;
          }
      } else {
#pragma unroll
        for (int c = 0; c < 4; ++c)
#pragma unroll
          for (int r = 0; r < 4; ++r) {
            float p = exp2f(sst[c][qf][r] - m[qf]);
            sst[c][qf][r] = p;
            partial += p;
          }
      }
      // overflow guard (rare): recover max from p, rescale in-register.
      if (!__all(partial <= 16777216.0f)) {
        float pm = sst[0][qf][0];
#pragma unroll
        for (int c = 0; c < 4; ++c)
#pragma unroll
          for (int r = 0; r < 4; ++r) pm = fmaxf(pm, sst[c][qf][r]);
        pm = fmaxf(pm, __shfl_xor(pm, 16));
        pm = fmaxf(pm, __shfl_xor(pm, 32));
        float mnew = log2f(pm) + m[qf];
        float cs = exp2f(m[qf] - mnew);
        m[qf] = mnew;
        mz[qf] = 0;
        lsum[qf] *= cs;
        partial *= cs;
#pragma unroll
        for (int c = 0; c < 4; ++c)
#pragma unroll
          for (int r = 0; r < 4; ++r) sst[c][qf][r] *= cs;
#pragma unroll
        for (int vf = 0; vf < 2; ++vf)
#pragma unroll
          for (int r = 0; r < 4; ++r) acc[vf][qf][r] *= cs;
      }
      partial += __shfl_xor(partial, 16);
      partial += __shfl_xor(partial, 32);
      lsum[qf] += partial;
#pragma unroll
      for (int c = 0; c < 4; ++c) {
        uint2 st;
        st.x = pack2(sst[c][qf][0], sst[c][qf][1]);
        st.y = pack2(sst[c][qf][2], sst[c][qf][3]);
        *reinterpret_cast<uint2*>(&P_lds[w][qf * 16 + ln][c * 16 + 4 * g]) = st;
      }
    }
#pragma unroll
    for (int hv = 0; hv < 2; ++hv) {
      short8 vfr[2];
#pragma unroll
      for (int vf = 0; vf < 2; ++vf)
        vfr[vf] = *reinterpret_cast<const short8*>(vp + (size_t)(vf * 16 + ln) * S + kv0 + hv * 32 + 8 * g);
#pragma unroll
      for (int qf = 0; qf < 2; ++qf) {
        short8 pf = *reinterpret_cast<const short8*>(&P_lds[w][qf * 16 + ln][hv * 32 + 8 * g]);
#pragma unroll
        for (int vf = 0; vf < 2; ++vf)
          acc[vf][qf] = __builtin_amdgcn_mfma_f32_16x16x32_bf16(vfr[vf], pf, acc[vf][qf], 0, 0, 0);
      }
    }
  }
  // ---- merge 4 kv-partials ----
  __syncthreads();  // all P reads done; smem becomes mbuf[w_q][slot][lane][20]
  if (w_kv) {
    float* mb = smem_f + ((w_q * 3 + (w_kv - 1)) * 64 + lane) * 20;
    mb[0] = m[0]; mb[1] = m[1]; mb[2] = lsum[0]; mb[3] = lsum[1];
#pragma unroll
    for (int vf = 0; vf < 2; ++vf)
#pragma unroll
      for (int qf = 0; qf < 2; ++qf)
#pragma unroll
        for (int r = 0; r < 4; ++r) mb[4 + (vf * 2 + qf) * 4 + r] = acc[vf][qf][r];
  }
  __syncthreads();
  if (w_kv == 0) {
    const float* mb0 = smem_f + ((w_q * 3 + 0) * 64 + lane) * 20;
    const float* mb1 = smem_f + ((w_q * 3 + 1) * 64 + lane) * 20;
    const float* mb2 = smem_f + ((w_q * 3 + 2) * 64 + lane) * 20;
    int b_ = bh >> 2, h = bh & 3;
#pragma unroll
    for (int qf = 0; qf < 2; ++qf) {
      float mt = fmaxf(fmaxf(m[qf], mb0[qf]), fmaxf(mb1[qf], mb2[qf]));
      float e0 = exp2f(m[qf] - mt);
      float e1 = exp2f(mb0[qf] - mt);
      float e2 = exp2f(mb1[qf] - mt);
      float e3 = exp2f(mb2[qf] - mt);
      float lt = lsum[qf] * e0 + mb0[2 + qf] * e1 + mb1[2 + qf] * e2 + mb2[2 + qf] * e3;
      float inv = 1.0f / lt;
      int qrow = qbase + qf * 16 + ln;
#pragma unroll
      for (int vf = 0; vf < 2; ++vf) {
        int dh0 = vf * 16 + 4 * g;
        int ai = 4 + (vf * 2 + qf) * 4;
        float o[4];
#pragma unroll
        for (int r = 0; r < 4; ++r)
          o[r] = (acc[vf][qf][r] * e0 + mb0[ai + r] * e1 + mb1[ai + r] * e2 + mb2[ai + r] * e3) * inv;
        uint2 st;
        st.x = pack2(o[0], o[1]);
        st.y = pack2(o[2], o[3]);
        *reinterpret_cast<uint2*>(ao + ((size_t)(b_ * S + qrow)) * D + h * DH + dh0) = st;
      }
    }
  }
}

// ---------------- out-proj + residual + Minkowski LN (K-split 2x64) ----------------
__global__ __launch_bounds__(512) void projln_kernel(
    const unsigned short* __restrict__ ao, const unsigned short* __restrict__ woT,
    const float* __restrict__ bo, const float* __restrict__ x,
    const float* __restrict__ g1t, const float* __restrict__ b1t,
    const float* __restrict__ g1s, const float* __restrict__ b1s,
    float* __restrict__ x1, unsigned short* __restrict__ x1b) {
  __shared__ float part[4][16][132];
  int w = threadIdx.x >> 6, lane = threadIdx.x & 63;
  int g = lane >> 4, ln = lane & 15;
  int wm = w >> 1, wk = w & 1;
  int row0 = blockIdx.x * 64 + wm * 16;
  f32x4 acc[8];
#pragma unroll
  for (int c = 0; c < 8; ++c) acc[c] = f32x4{0.f, 0.f, 0.f, 0.f};
  gemm_tileK<128, 128, 64>(ao, woT, row0, wk * 64, ln, g, acc);
  if (wk == 1) {
#pragma unroll
    for (int c = 0; c < 8; ++c)
      *reinterpret_cast<f32x4*>(&part[wm][ln][c * 16 + 4 * g]) = acc[c];
  }
  __syncthreads();
  if (wk == 1) return;
  int t = row0 + ln;
  float rv[8][4];
#pragma unroll
  for (int c = 0; c < 8; ++c) {
    int nc = c * 16 + 4 * g;
    f32x4 pp = *reinterpret_cast<const f32x4*>(&part[wm][ln][nc]);
    f32x4 bi = *reinterpret_cast<const f32x4*>(bo + nc);
    f32x4 xr = *reinterpret_cast<const f32x4*>(x + (size_t)t * D + nc);
#pragma unroll
    for (int r = 0; r < 4; ++r) rv[c][r] = acc[c][r] + pp[r] + bi[r] + xr[r];
  }
  float st = 0.f, ss = 0.f;
#pragma unroll
  for (int c = 0; c < 2; ++c)
#pragma unroll
    for (int r = 0; r < 4; ++r) st += rv[c][r];
#pragma unroll
  for (int c = 2; c < 8; ++c)
#pragma unroll
    for (int r = 0; r < 4; ++r) ss += rv[c][r];
  st += __shfl_xor(st, 16); st += __shfl_xor(st, 32);
  ss += __shfl_xor(ss, 16); ss += __shfl_xor(ss, 32);
  float mut = st * (1.f / 32.f), mus = ss * (1.f / 96.f);
  float vt = 0.f, vs = 0.f;
#pragma unroll
  for (int c = 0; c < 2; ++c)
#pragma unroll
    for (int r = 0; r < 4; ++r) { float d = rv[c][r] - mut; vt += d * d; }
#pragma unroll
  for (int c = 2; c < 8; ++c)
#pragma unroll
    for (int r = 0; r < 4; ++r) { float d = rv[c][r] - mus; vs += d * d; }
  vt += __shfl_xor(vt, 16); vt += __shfl_xor(vt, 32);
  vs += __shfl_xor(vs, 16); vs += __shfl_xor(vs, 32);
  float rst = rsqrtf(vt * (1.f / 32.f) + EPSV);
  float rss = rsqrtf(vs * (1.f / 96.f) + EPSV);
#pragma unroll
  for (int c = 0; c < 8; ++c) {
    int nc = c * 16 + 4 * g;
    f32x4 ga, bb;
    if (c < 2) {
      ga = *reinterpret_cast<const f32x4*>(g1t + nc);
      bb = *reinterpret_cast<const f32x4*>(b1t + nc);
    } else {
      ga = *reinterpret_cast<const f32x4*>(g1s + nc - 32);
      bb = *reinterpret_cast<const f32x4*>(b1s + nc - 32);
    }
    f32x4 o4;
#pragma unroll
    for (int r = 0; r < 4; ++r)
      o4[r] = (c < 2) ? (rv[c][r] - mut) * rst * ga[r] + bb[r]
                      : (rv[c][r] - mus) * rss * ga[r] + bb[r];
    *reinterpret_cast<f32x4*>(x1 + (size_t)t * D + nc) = o4;
    uint2 sb;
    sb.x = pack2(o4[0], o4[1]);
    sb.y = pack2(o4[2], o4[3]);
    *reinterpret_cast<uint2*>(x1b + (size_t)t * D + nc) = sb;
  }
}

// ---------------- FFN1 + exact GELU ----------------
__global__ __launch_bounds__(256) void ffn1_kernel(
    const unsigned short* __restrict__ x1b, const unsigned short* __restrict__ w1T,
    const float* __restrict__ bf1, unsigned short* __restrict__ h) {
  int w = threadIdx.x >> 6, lane = threadIdx.x & 63;
  int g = lane >> 4, ln = lane & 15;
  int row0 = blockIdx.x * 64 + w * 16;
  int n0 = blockIdx.y * 128;
  f32x4 acc[8];
#pragma unroll
  for (int c = 0; c < 8; ++c) acc[c] = f32x4{0.f, 0.f, 0.f, 0.f};
  gemm_tile<128, true>(x1b, w1T, row0, n0, ln, g, acc);
  int t = row0 + ln;
#pragma unroll
  for (int c = 0; c < 8; ++c) {
    int nc = n0 + c * 16 + 4 * g;
    f32x4 bi = *reinterpret_cast<const f32x4*>(bf1 + nc);
    float ge[4];
#pragma unroll
    for (int r = 0; r < 4; ++r) {
      float v = acc[c][r] + bi[r];
      ge[r] = 0.5f * v * (1.0f + erff(v * 0.70710678118654752f));
    }
    uint2 stv;
    stv.x = pack2(ge[0], ge[1]);
    stv.y = pack2(ge[2], ge[3]);
    *reinterpret_cast<uint2*>(h + (size_t)t * 512 + nc) = stv;
  }
}

// ---------------- FFN2 + residual + Minkowski LN (K-split 2x256) ----------------
__global__ __launch_bounds__(512) void ffn2_kernel(
    const unsigned short* __restrict__ h, const unsigned short* __restrict__ w2T,
    const float* __restrict__ bf2, const float* __restrict__ x1,
    const float* __restrict__ g2t, const float* __restrict__ b2t,
    const float* __restrict__ g2s, const float* __restrict__ b2s,
    float* __restrict__ out) {
  __shared__ float part[4][16][132];
  int w = threadIdx.x >> 6, lane = threadIdx.x & 63;
  int g = lane >> 4, ln = lane & 15;
  int wm = w >> 1, wk = w & 1;
  int row0 = blockIdx.x * 64 + wm * 16;
  f32x4 acc[8];
#pragma unroll
  for (int c = 0; c < 8; ++c) acc[c] = f32x4{0.f, 0.f, 0.f, 0.f};
  gemm_tileK<512, 512, 256>(h, w2T, row0, wk * 256, ln, g, acc);
  if (wk == 1) {
#pragma unroll
    for (int c = 0; c < 8; ++c)
      *reinterpret_cast<f32x4*>(&part[wm][ln][c * 16 + 4 * g]) = acc[c];
  }
  __syncthreads();
  if (wk == 1) return;
  int t = row0 + ln;
  float rv[8][4];
#pragma unroll
  for (int c = 0; c < 8; ++c) {
    int nc = c * 16 + 4 * g;
    f32x4 pp = *reinterpret_cast<const f32x4*>(&part[wm][ln][nc]);
    f32x4 bi = *reinterpret_cast<const f32x4*>(bf2 + nc);
    f32x4 xr = *reinterpret_cast<const f32x4*>(x1 + (size_t)t * D + nc);
#pragma unroll
    for (int r = 0; r < 4; ++r) rv[c][r] = acc[c][r] + pp[r] + bi[r] + xr[r];
  }
  float st = 0.f, ss = 0.f;
#pragma unroll
  for (int c = 0; c < 2; ++c)
#pragma unroll
    for (int r = 0; r < 4; ++r) st += rv[c][r];
#pragma unroll
  for (int c = 2; c < 8; ++c)
#pragma unroll
    for (int r = 0; r < 4; ++r) ss += rv[c][r];
  st += __shfl_xor(st, 16); st += __shfl_xor(st, 32);
  ss += __shfl_xor(ss, 16); ss += __shfl_xor(ss, 32);
  float mut = st * (1.f / 32.f), mus = ss * (1.f / 96.f);
  float vt = 0.f, vs = 0.f;
#pragma unroll
  for (int c = 0; c < 2; ++c)
#pragma unroll
    for (int r = 0; r < 4; ++r) { float d = rv[c][r] - mut; vt += d * d; }
#pragma unroll
  for (int c = 2; c < 8; ++c)
#pragma unroll
    for (int r = 0; r < 4; ++r) { float d = rv[c][r] - mus; vs += d * d; }
  vt += __shfl_xor(vt, 16); vt += __shfl_xor(vt, 32);
  vs += __shfl_xor(vs, 16); vs += __shfl_xor(vs, 32);
  float rst = rsqrtf(vt * (1.f / 32.f) + EPSV);
  float rss = rsqrtf(vs * (1.f / 96.f) + EPSV);
#pragma unroll
  for (int c = 0; c < 8; ++c) {
    int nc = c * 16 + 4 * g;
    f32x4 ga, bb;
    if (c < 2) {
      ga = *reinterpret_cast<const f32x4*>(g2t + nc);
      bb = *reinterpret_cast<const f32x4*>(b2t + nc);
    } else {
      ga = *reinterpret_cast<const f32x4*>(g2s + nc - 32);
      bb = *reinterpret_cast<const f32x4*>(b2s + nc - 32);
    }
    f32x4 o4;
#pragma unroll
    for (int r = 0; r < 4; ++r)
      o4[r] = (c < 2) ? (rv[c][r] - mut) * rst * ga[r] + bb[r]
                      : (rv[c][r] - mus) * rss * ga[r] + bb[r];
    *reinterpret_cast<f32x4*>(out + (size_t)t * D + nc) = o4;
  }
}

extern "C" void kernel_launch(void* const* d_in, const int* in_sizes, int n_in,
                              void* d_out, int out_size, void* d_ws, size_t ws_size,
                              hipStream_t stream) {
  (void)in_sizes; (void)n_in; (void)out_size; (void)ws_size;
  const float* x   = (const float*)d_in[0];
  const float* Wq  = (const float*)d_in[1];
  const float* bq  = (const float*)d_in[2];
  const float* Wk  = (const float*)d_in[3];
  const float* bk  = (const float*)d_in[4];
  const float* Wv  = (const float*)d_in[5];
  const float* bv  = (const float*)d_in[6];
  const float* Wo  = (const float*)d_in[7];
  const float* bo  = (const float*)d_in[8];
  const float* g1t = (const float*)d_in[9];
  const float* b1t = (const float*)d_in[10];
  const float* g1s = (const float*)d_in[11];
  const float* b1s = (const float*)d_in[12];
  const float* W1  = (const float*)d_in[13];
  const float* bf1 = (const float*)d_in[14];
  const float* W2  = (const float*)d_in[15];
  const float* bf2 = (const float*)d_in[16];
  const float* g2t = (const float*)d_in[17];
  const float* b2t = (const float*)d_in[18];
  const float* g2s = (const float*)d_in[19];
  const float* b2s = (const float*)d_in[20];

  char* ws = (char*)d_ws;
  unsigned short* xb  = (unsigned short*)(ws);                 // 16384x128 bf16
  unsigned short* wqT = (unsigned short*)(ws + 4194304);
  unsigned short* wkT = wqT + 16384;
  unsigned short* wvT = wkT + 16384;
  unsigned short* woT = wvT + 16384;
  unsigned short* w1T = woT + 16384;   // [512][128]
  unsigned short* w2T = w1T + 65536;   // [128][512]
  unsigned short* qb  = w2T + 65536;   // [8][4][2048][32]
  unsigned short* kb  = qb + 2097152;
  unsigned short* vT  = kb + 2097152;  // [8][4][32][2048]
  unsigned short* ao  = vT + 2097152;  // [16384][128]
  float* x1           = (float*)(ao + 2097152);      // [16384][128] f32
  unsigned short* x1b = (unsigned short*)(x1 + 2097152);
  unsigned short* hbf = x1b + 2097152; // [16384][512]
  float* outp = (float*)d_out;

  prep_kernel<<<1792, 256, 0, stream>>>(x, Wq, Wk, Wv, Wo, W1, W2,
                                        xb, wqT, wkT, wvT, woT, w1T, w2T);
  qkv_kernel<<<dim3(256, 3), 256, 0, stream>>>(xb, wqT, wkT, wvT, bq, bk, bv, qb, kb, vT);
  attn_kernel<<<dim3(32, 32), 512, 0, stream>>>(qb, kb, vT, ao);
  projln_kernel<<<256, 512, 0, stream>>>(ao, woT, bo, x, g1t, b1t, g1s, b1s, x1, x1b);
  ffn1_kernel<<<dim3(256, 4), 256, 0, stream>>>(x1b, w1T, bf1, hbf);
  ffn2_kernel<<<256, 512, 0, stream>>>(hbf, w2T, bf2, x1, g2t, b2t, g2s, b2s, outp);
}

// Round 5
// 115.754 us; speedup vs baseline: 1.7364x; 1.1843x over previous
//
#include <hip/hip_runtime.h>
#include <hip/hip_bf16.h>

#define DEV __device__ __forceinline__

typedef __attribute__((ext_vector_type(8))) short short8;
typedef __attribute__((ext_vector_type(4))) float f32x4;

constexpr int D   = 128;
constexpr int S   = 2048;
constexpr int Hh  = 4;
constexpr int DH  = 32;
// 1/sqrt(32) * log2(e): QK^T logits land directly in exp2 domain.
constexpr float QSCALE = 0.17677669529663687f * 1.4426950408889634f;
constexpr float EPSV = 1e-5f;

DEV unsigned short f2b(float f) {
  __hip_bfloat16 h = __float2bfloat16(f);
  return *reinterpret_cast<unsigned short*>(&h);
}
DEV unsigned pack2(float a, float b) {
  return (unsigned)f2b(a) | ((unsigned)f2b(b) << 16);
}

// ---------------- prep: x -> bf16, weights -> bf16 transposed ----------------
__global__ __launch_bounds__(256) void prep_kernel(
    const float* __restrict__ x,
    const float* __restrict__ Wq, const float* __restrict__ Wk,
    const float* __restrict__ Wv, const float* __restrict__ Wo,
    const float* __restrict__ W1, const float* __restrict__ W2,
    unsigned short* __restrict__ xb,
    unsigned short* __restrict__ wqT, unsigned short* __restrict__ wkT,
    unsigned short* __restrict__ wvT, unsigned short* __restrict__ woT,
    unsigned short* __restrict__ w1T, unsigned short* __restrict__ w2T) {
  int b = blockIdx.x, t = threadIdx.x;
  if (b < 1024) {
    int i8 = (b * 256 + t) * 8;
    const float4* p = reinterpret_cast<const float4*>(x + i8);
    float4 v0 = p[0], v1 = p[1];
    short8 o;
    o[0] = (short)f2b(v0.x); o[1] = (short)f2b(v0.y);
    o[2] = (short)f2b(v0.z); o[3] = (short)f2b(v0.w);
    o[4] = (short)f2b(v1.x); o[5] = (short)f2b(v1.y);
    o[6] = (short)f2b(v1.z); o[7] = (short)f2b(v1.w);
    *reinterpret_cast<short8*>(xb + i8) = o;
    return;
  }
  const float* src; unsigned short* dst; int K, N, base;
  if      (b < 1088) { src = Wq; dst = wqT; K = 128; N = 128; base = 1024; }
  else if (b < 1152) { src = Wk; dst = wkT; K = 128; N = 128; base = 1088; }
  else if (b < 1216) { src = Wv; dst = wvT; K = 128; N = 128; base = 1152; }
  else if (b < 1280) { src = Wo; dst = woT; K = 128; N = 128; base = 1216; }
  else if (b < 1536) { src = W1; dst = w1T; K = 128; N = 512; base = 1280; }
  else               { src = W2; dst = w2T; K = 512; N = 128; base = 1536; }
  int idx = (b - base) * 256 + t;
  int k = idx / N, n = idx - k * N;
  dst[n * K + k] = f2b(src[idx]);
}

// ---------------- GEMM tile core (qkv) ----------------
template <int KDIM, bool SWAP>
DEV void gemm_tile(const unsigned short* __restrict__ A,
                   const unsigned short* __restrict__ BT,
                   int row0, int n0, int ln, int g, f32x4 acc[8]) {
#pragma unroll
  for (int ks = 0; ks < KDIM; ks += 32) {
    short8 a = *reinterpret_cast<const short8*>(A + (size_t)(row0 + ln) * KDIM + ks + 8 * g);
#pragma unroll
    for (int c = 0; c < 8; ++c) {
      short8 b = *reinterpret_cast<const short8*>(BT + (size_t)(n0 + c * 16 + ln) * KDIM + ks + 8 * g);
      if constexpr (SWAP)
        acc[c] = __builtin_amdgcn_mfma_f32_16x16x32_bf16(b, a, acc[c], 0, 0, 0);
      else
        acc[c] = __builtin_amdgcn_mfma_f32_16x16x32_bf16(a, b, acc[c], 0, 0, 0);
    }
  }
}

// ---------------- QKV projection ----------------
__global__ __launch_bounds__(256) void qkv_kernel(
    const unsigned short* __restrict__ xb,
    const unsigned short* __restrict__ wqT, const unsigned short* __restrict__ wkT,
    const unsigned short* __restrict__ wvT,
    const float* __restrict__ bq, const float* __restrict__ bk, const float* __restrict__ bv,
    unsigned short* __restrict__ q, unsigned short* __restrict__ k,
    unsigned short* __restrict__ vT) {
  int w = threadIdx.x >> 6, lane = threadIdx.x & 63;
  int g = lane >> 4, ln = lane & 15;
  int z = blockIdx.y;
  int row0 = blockIdx.x * 64 + w * 16;
  const unsigned short* BT = (z == 0) ? wqT : (z == 1) ? wkT : wvT;
  const float* bias = (z == 0) ? bq : (z == 1) ? bk : bv;
  f32x4 acc[8];
#pragma unroll
  for (int c = 0; c < 8; ++c) acc[c] = f32x4{0.f, 0.f, 0.f, 0.f};
  if (z == 2) {
    gemm_tile<128, false>(xb, BT, row0, 0, ln, g, acc);
#pragma unroll
    for (int c = 0; c < 8; ++c) {
      int n = c * 16 + ln;
      int h = n >> 5, dh = n & 31;
      float bi = bias[n];
      int t0 = row0 + 4 * g;
      int b_ = t0 >> 11, s0 = t0 & 2047;
      size_t off = ((size_t)(b_ * Hh + h) * DH + dh) * S + s0;
      uint2 st;
      st.x = pack2(acc[c][0] + bi, acc[c][1] + bi);
      st.y = pack2(acc[c][2] + bi, acc[c][3] + bi);
      *reinterpret_cast<uint2*>(vT + off) = st;
    }
  } else {
    gemm_tile<128, true>(xb, BT, row0, 0, ln, g, acc);
    unsigned short* dst = (z == 0) ? q : k;
    int t = row0 + ln;
    int b_ = t >> 11, s = t & 2047;
#pragma unroll
    for (int c = 0; c < 8; ++c) {
      int nc = c * 16 + 4 * g;
      int h = nc >> 5, dh0 = nc & 31;
      f32x4 bi = *reinterpret_cast<const f32x4*>(bias + nc);
      float f = 1.0f;
      if (z == 0) f = (dh0 < 8) ? -QSCALE : QSCALE;
      float v0 = (acc[c][0] + bi[0]) * f, v1 = (acc[c][1] + bi[1]) * f;
      float v2 = (acc[c][2] + bi[2]) * f, v3 = (acc[c][3] + bi[3]) * f;
      uint2 st;
      st.x = pack2(v0, v1);
      st.y = pack2(v2, v3);
      *reinterpret_cast<uint2*>(dst + ((size_t)(b_ * Hh + h) * S + s) * DH + dh0) = st;
    }
  }
}

// ---------------- flash attention ----------------
// grid: (32 q-tiles of 64, 32 bh). block: 512 thr = 8 waves.
// wave w: w_q = w>>2 (32 q rows), w_kv = w&3 (512-kv quarter). No inner
// barriers (P wave-private); 4-way partial merge at the end via LDS overlay.
// NOTE: (512,4) not (512,8) — 8 waves/EU caps VGPR at 64 and the ~70-reg
// working set spills to scratch (round-3 post-mortem: 270 MB WRITE_SIZE).
__global__ __launch_bounds__(512, 4) void attn_kernel(
    const unsigned short* __restrict__ q, const unsigned short* __restrict__ k,
    const unsigned short* __restrict__ vT, unsigned short* __restrict__ ao) {
  __shared__ float smem_f[9216];  // 36864 B: P_lds during loop, mbuf after
  unsigned short (*P_lds)[32][72] = reinterpret_cast<unsigned short(*)[32][72]>(smem_f);
  int w = threadIdx.x >> 6, lane = threadIdx.x & 63;
  int g = lane >> 4, ln = lane & 15;
  int w_q = w >> 2, w_kv = w & 3;
  int bh = blockIdx.y;
  int qbase = blockIdx.x * 64 + w_q * 32;
  const unsigned short* qp = q + (size_t)bh * S * DH;
  const unsigned short* kp = k + (size_t)bh * S * DH;
  const unsigned short* vp = vT + (size_t)bh * DH * S;

  short8 qfr[2];
#pragma unroll
  for (int qf = 0; qf < 2; ++qf)
    qfr[qf] = *reinterpret_cast<const short8*>(qp + (size_t)(qbase + qf * 16 + ln) * DH + 8 * g);

  float m[2] = {0.f, 0.f};
  float lsum[2] = {0.f, 0.f};
  int mz[2] = {1, 1};  // m[qf]==0 fast-path flag (wave-uniform)
  f32x4 acc[2][2];     // [vf][qf] O^T fragments
#pragma unroll
  for (int a = 0; a < 2; ++a)
#pragma unroll
    for (int b = 0; b < 2; ++b) acc[a][b] = f32x4{0.f, 0.f, 0.f, 0.f};

  for (int kt = 0; kt < 8; ++kt) {
    int kv0 = w_kv * 512 + kt * 64;
    short8 kf[4];
#pragma unroll
    for (int c = 0; c < 4; ++c)
      kf[c] = *reinterpret_cast<const short8*>(kp + (size_t)(kv0 + c * 16 + ln) * DH + 8 * g);
    f32x4 sst[4][2];
#pragma unroll
    for (int c = 0; c < 4; ++c)
#pragma unroll
      for (int qf = 0; qf < 2; ++qf)
        sst[c][qf] = __builtin_amdgcn_mfma_f32_16x16x32_bf16(kf[c], qfr[qf],
                                                             f32x4{0.f, 0.f, 0.f, 0.f}, 0, 0, 0);
#pragma unroll
    for (int qf = 0; qf < 2; ++qf) {
      float partial = 0.f;
      if (__builtin_amdgcn_readfirstlane(mz[qf])) {
#pragma unroll
        for (int c = 0; c < 4; ++c)
#pragma unroll
          for (int r = 0; r < 4; ++r) {
            float p = __builtin_amdgcn_exp2f(sst[c][qf][r]);
            sst[c][qf][r] = p;
            partial += p;
          }
      } else {
#pragma unroll
        for (int c = 0; c < 4; ++c)
#pragma unroll
          for (int r = 0; r < 4; ++r) {
            float p = __builtin_amdgcn_exp2f(sst[c][qf][r] - m[qf]);
            sst[c][qf][r] = p;
            partial += p;
          }
      }
      // overflow guard (rare): recover max from p, rescale in-register.
      if (!__all(partial <= 16777216.0f)) {
        float pm = sst[0][qf][0];
#pragma unroll
        for (int c = 0; c < 4; ++c)
#pragma unroll
          for (int r = 0; r < 4; ++r) pm = fmaxf(pm, sst[c][qf][r]);
        pm = fmaxf(pm, __shfl_xor(pm, 16));
        pm = fmaxf(pm, __shfl_xor(pm, 32));
        float mnew = __builtin_amdgcn_logf(pm) + m[qf];  // v_log_f32 = log2
        float cs = __builtin_amdgcn_exp2f(m[qf] - mnew);
        m[qf] = mnew;
        mz[qf] = 0;
        lsum[qf] *= cs;
        partial *= cs;
#pragma unroll
        for (int c = 0; c < 4; ++c)
#pragma unroll
          for (int r = 0; r < 4; ++r) sst[c][qf][r] *= cs;
#pragma unroll
        for (int vf = 0; vf < 2; ++vf)
#pragma unroll
          for (int r = 0; r < 4; ++r) acc[vf][qf][r] *= cs;
      }
      partial += __shfl_xor(partial, 16);
      partial += __shfl_xor(partial, 32);
      lsum[qf] += partial;
#pragma unroll
      for (int c = 0; c < 4; ++c) {
        uint2 st;
        st.x = pack2(sst[c][qf][0], sst[c][qf][1]);
        st.y = pack2(sst[c][qf][2], sst[c][qf][3]);
        *reinterpret_cast<uint2*>(&P_lds[w][qf * 16 + ln][c * 16 + 4 * g]) = st;
      }
    }
#pragma unroll
    for (int hv = 0; hv < 2; ++hv) {
      short8 vfr[2];
#pragma unroll
      for (int vf = 0; vf < 2; ++vf)
        vfr[vf] = *reinterpret_cast<const short8*>(vp + (size_t)(vf * 16 + ln) * S + kv0 + hv * 32 + 8 * g);
#pragma unroll
      for (int qf = 0; qf < 2; ++qf) {
        short8 pf = *reinterpret_cast<const short8*>(&P_lds[w][qf * 16 + ln][hv * 32 + 8 * g]);
#pragma unroll
        for (int vf = 0; vf < 2; ++vf)
          acc[vf][qf] = __builtin_amdgcn_mfma_f32_16x16x32_bf16(vfr[vf], pf, acc[vf][qf], 0, 0, 0);
      }
    }
  }
  // ---- merge 4 kv-partials ----
  __syncthreads();  // all P reads done; smem becomes mbuf[w_q][slot][lane][20]
  if (w_kv) {
    float* mb = smem_f + ((w_q * 3 + (w_kv - 1)) * 64 + lane) * 20;
    mb[0] = m[0]; mb[1] = m[1]; mb[2] = lsum[0]; mb[3] = lsum[1];
#pragma unroll
    for (int vf = 0; vf < 2; ++vf)
#pragma unroll
      for (int qf = 0; qf < 2; ++qf)
#pragma unroll
        for (int r = 0; r < 4; ++r) mb[4 + (vf * 2 + qf) * 4 + r] = acc[vf][qf][r];
  }
  __syncthreads();
  if (w_kv == 0) {
    const float* mb0 = smem_f + ((w_q * 3 + 0) * 64 + lane) * 20;
    const float* mb1 = smem_f + ((w_q * 3 + 1) * 64 + lane) * 20;
    const float* mb2 = smem_f + ((w_q * 3 + 2) * 64 + lane) * 20;
    int b_ = bh >> 2, h = bh & 3;
#pragma unroll
    for (int qf = 0; qf < 2; ++qf) {
      float mt = fmaxf(fmaxf(m[qf], mb0[qf]), fmaxf(mb1[qf], mb2[qf]));
      float e0 = __builtin_amdgcn_exp2f(m[qf] - mt);
      float e1 = __builtin_amdgcn_exp2f(mb0[qf] - mt);
      float e2 = __builtin_amdgcn_exp2f(mb1[qf] - mt);
      float e3 = __builtin_amdgcn_exp2f(mb2[qf] - mt);
      float lt = lsum[qf] * e0 + mb0[2 + qf] * e1 + mb1[2 + qf] * e2 + mb2[2 + qf] * e3;
      float inv = 1.0f / lt;
      int qrow = qbase + qf * 16 + ln;
#pragma unroll
      for (int vf = 0; vf < 2; ++vf) {
        int dh0 = vf * 16 + 4 * g;
        int ai = 4 + (vf * 2 + qf) * 4;
        float o[4];
#pragma unroll
        for (int r = 0; r < 4; ++r)
          o[r] = (acc[vf][qf][r] * e0 + mb0[ai + r] * e1 + mb1[ai + r] * e2 + mb2[ai + r] * e3) * inv;
        uint2 st;
        st.x = pack2(o[0], o[1]);
        st.y = pack2(o[2], o[3]);
        *reinterpret_cast<uint2*>(ao + ((size_t)(b_ * S + qrow)) * D + h * DH + dh0) = st;
      }
    }
  }
}

// ---------------- fused tail: out-proj + res + LN1 + FFN1/GELU + FFN2 + res + LN2 ----------------
// 512 blocks x 8 waves; 32 rows per block. Wave (wm = w&1: 16-row half,
// wn = w>>1: col quarter). x1 carried in registers; x1b / h staged in LDS.
__global__ __launch_bounds__(512, 2) void tail_kernel(
    const unsigned short* __restrict__ ao, const unsigned short* __restrict__ woT,
    const float* __restrict__ bo, const float* __restrict__ x,
    const float* __restrict__ g1t, const float* __restrict__ b1t,
    const float* __restrict__ g1s, const float* __restrict__ b1s,
    const unsigned short* __restrict__ w1T, const float* __restrict__ bf1,
    const unsigned short* __restrict__ w2T, const float* __restrict__ bf2,
    const float* __restrict__ g2t, const float* __restrict__ b2t,
    const float* __restrict__ g2s, const float* __restrict__ b2s,
    float* __restrict__ out) {
  __shared__ unsigned short xbl[32][136];  // x1 bf16, row stride 272B (16B-mult, bank-drift 4)
  __shared__ unsigned short hl[32][520];   // h bf16, row stride 1040B (16B-mult, bank-drift 4)
  __shared__ float stats[2][4][16][2];     // per-(wm,wn,row) {sum, sumsq}
  int w = threadIdx.x >> 6, lane = threadIdx.x & 63;
  int g = lane >> 4, ln = lane & 15;
  int wm = w & 1, wn = w >> 1;
  int r0 = blockIdx.x * 32;
  int row = r0 + wm * 16 + ln;
  int lrow = wm * 16 + ln;

  // ---- phase 1: out-proj (16 rows x 32 cols per wave, full K=128) ----
  f32x4 acc1[2];
  acc1[0] = f32x4{0.f, 0.f, 0.f, 0.f};
  acc1[1] = f32x4{0.f, 0.f, 0.f, 0.f};
#pragma unroll
  for (int ks = 0; ks < 128; ks += 32) {
    short8 a = *reinterpret_cast<const short8*>(ao + (size_t)row * 128 + ks + 8 * g);
#pragma unroll
    for (int c2 = 0; c2 < 2; ++c2) {
      short8 b = *reinterpret_cast<const short8*>(woT + (size_t)(wn * 32 + c2 * 16 + ln) * 128 + ks + 8 * g);
      acc1[c2] = __builtin_amdgcn_mfma_f32_16x16x32_bf16(b, a, acc1[c2], 0, 0, 0);
    }
  }
  float rv[2][4];
  {
    float sum = 0.f, sq = 0.f;
#pragma unroll
    for (int c2 = 0; c2 < 2; ++c2) {
      int nc = wn * 32 + c2 * 16 + 4 * g;
      f32x4 bi = *reinterpret_cast<const f32x4*>(bo + nc);
      f32x4 xr = *reinterpret_cast<const f32x4*>(x + (size_t)row * D + nc);
#pragma unroll
      for (int r = 0; r < 4; ++r) {
        float v = acc1[c2][r] + bi[r] + xr[r];
        rv[c2][r] = v;
        sum += v; sq += v * v;
      }
    }
    sum += __shfl_xor(sum, 16); sum += __shfl_xor(sum, 32);
    sq  += __shfl_xor(sq, 16);  sq  += __shfl_xor(sq, 32);
    stats[wm][wn][ln][0] = sum;
    stats[wm][wn][ln][1] = sq;
  }
  __syncthreads();
  f32x4 xv[2];  // x1 (LN1 output) kept in registers for phase-3 residual
  {
    float mu, rs;
    if (wn == 0) {  // time block = cols 0..31 exactly
      float s = stats[wm][0][ln][0], q2 = stats[wm][0][ln][1];
      mu = s * (1.f / 32.f);
      rs = rsqrtf(q2 * (1.f / 32.f) - mu * mu + EPSV);
    } else {        // space block = cols 32..127
      float s  = stats[wm][1][ln][0] + stats[wm][2][ln][0] + stats[wm][3][ln][0];
      float q2 = stats[wm][1][ln][1] + stats[wm][2][ln][1] + stats[wm][3][ln][1];
      mu = s * (1.f / 96.f);
      rs = rsqrtf(q2 * (1.f / 96.f) - mu * mu + EPSV);
    }
#pragma unroll
    for (int c2 = 0; c2 < 2; ++c2) {
      int nc = wn * 32 + c2 * 16 + 4 * g;
      f32x4 ga, bb;
      if (wn == 0) { ga = *reinterpret_cast<const f32x4*>(g1t + nc);
                     bb = *reinterpret_cast<const f32x4*>(b1t + nc); }
      else         { ga = *reinterpret_cast<const f32x4*>(g1s + nc - 32);
                     bb = *reinterpret_cast<const f32x4*>(b1s + nc - 32); }
#pragma unroll
      for (int r = 0; r < 4; ++r)
        xv[c2][r] = (rv[c2][r] - mu) * rs * ga[r] + bb[r];
      uint2 sb;
      sb.x = pack2(xv[c2][0], xv[c2][1]);
      sb.y = pack2(xv[c2][2], xv[c2][3]);
      *reinterpret_cast<uint2*>(&xbl[lrow][nc]) = sb;
    }
  }
  __syncthreads();

  // ---- phase 2: ffn1 + exact GELU (16 rows x 128 of 512 cols per wave) ----
  {
    f32x4 acc2[8];
#pragma unroll
    for (int c = 0; c < 8; ++c) acc2[c] = f32x4{0.f, 0.f, 0.f, 0.f};
#pragma unroll
    for (int ks = 0; ks < 128; ks += 32) {
      short8 a = *reinterpret_cast<const short8*>(&xbl[lrow][ks + 8 * g]);
#pragma unroll
      for (int c = 0; c < 8; ++c) {
        short8 b = *reinterpret_cast<const short8*>(w1T + (size_t)(wn * 128 + c * 16 + ln) * 128 + ks + 8 * g);
        acc2[c] = __builtin_amdgcn_mfma_f32_16x16x32_bf16(b, a, acc2[c], 0, 0, 0);
      }
    }
#pragma unroll
    for (int c = 0; c < 8; ++c) {
      int nc = wn * 128 + c * 16 + 4 * g;
      f32x4 bi = *reinterpret_cast<const f32x4*>(bf1 + nc);
      float ge[4];
#pragma unroll
      for (int r = 0; r < 4; ++r) {
        float v = acc2[c][r] + bi[r];
        ge[r] = 0.5f * v * (1.0f + erff(v * 0.70710678118654752f));
      }
      uint2 stv;
      stv.x = pack2(ge[0], ge[1]);
      stv.y = pack2(ge[2], ge[3]);
      *reinterpret_cast<uint2*>(&hl[lrow][nc]) = stv;
    }
  }
  __syncthreads();

  // ---- phase 3: ffn2 (16 rows x 32 cols per wave, full K=512) ----
  f32x4 acc3[2];
  acc3[0] = f32x4{0.f, 0.f, 0.f, 0.f};
  acc3[1] = f32x4{0.f, 0.f, 0.f, 0.f};
#pragma unroll
  for (int ks = 0; ks < 512; ks += 32) {
    short8 a = *reinterpret_cast<const short8*>(&hl[lrow][ks + 8 * g]);
#pragma unroll
    for (int c2 = 0; c2 < 2; ++c2) {
      short8 b = *reinterpret_cast<const short8*>(w2T + (size_t)(wn * 32 + c2 * 16 + ln) * 512 + ks + 8 * g);
      acc3[c2] = __builtin_amdgcn_mfma_f32_16x16x32_bf16(b, a, acc3[c2], 0, 0, 0);
    }
  }
  float rv2[2][4];
  {
    float sum = 0.f, sq = 0.f;
#pragma unroll
    for (int c2 = 0; c2 < 2; ++c2) {
      int nc = wn * 32 + c2 * 16 + 4 * g;
      f32x4 bi = *reinterpret_cast<const f32x4*>(bf2 + nc);
#pragma unroll
      for (int r = 0; r < 4; ++r) {
        float v = acc3[c2][r] + bi[r] + xv[c2][r];
        rv2[c2][r] = v;
        sum += v; sq += v * v;
      }
    }
    sum += __shfl_xor(sum, 16); sum += __shfl_xor(sum, 32);
    sq  += __shfl_xor(sq, 16);  sq  += __shfl_xor(sq, 32);
    stats[wm][wn][ln][0] = sum;   // stats region reused (phase-1 reads long done)
    stats[wm][wn][ln][1] = sq;
  }
  __syncthreads();
  {
    float mu, rs;
    if (wn == 0) {
      float s = stats[wm][0][ln][0], q2 = stats[wm][0][ln][1];
      mu = s * (1.f / 32.f);
      rs = rsqrtf(q2 * (1.f / 32.f) - mu * mu + EPSV);
    } else {
      float s  = stats[wm][1][ln][0] + stats[wm][2][ln][0] + stats[wm][3][ln][0];
      float q2 = stats[wm][1][ln][1] + stats[wm][2][ln][1] + stats[wm][3][ln][1];
      mu = s * (1.f / 96.f);
      rs = rsqrtf(q2 * (1.f / 96.f) - mu * mu + EPSV);
    }
#pragma unroll
    for (int c2 = 0; c2 < 2; ++c2) {
      int nc = wn * 32 + c2 * 16 + 4 * g;
      f32x4 ga, bb;
      if (wn == 0) { ga = *reinterpret_cast<const f32x4*>(g2t + nc);
                     bb = *reinterpret_cast<const f32x4*>(b2t + nc); }
      else         { ga = *reinterpret_cast<const f32x4*>(g2s + nc - 32);
                     bb = *reinterpret_cast<const f32x4*>(b2s + nc - 32); }
      f32x4 o4;
#pragma unroll
      for (int r = 0; r < 4; ++r)
        o4[r] = (rv2[c2][r] - mu) * rs * ga[r] + bb[r];
      *reinterpret_cast<f32x4*>(out + (size_t)row * D + nc) = o4;
    }
  }
}

extern "C" void kernel_launch(void* const* d_in, const int* in_sizes, int n_in,
                              void* d_out, int out_size, void* d_ws, size_t ws_size,
                              hipStream_t stream) {
  (void)in_sizes; (void)n_in; (void)out_size; (void)ws_size;
  const float* x   = (const float*)d_in[0];
  const float* Wq  = (const float*)d_in[1];
  const float* bq  = (const float*)d_in[2];
  const float* Wk  = (const float*)d_in[3];
  const float* bk  = (const float*)d_in[4];
  const float* Wv  = (const float*)d_in[5];
  const float* bv  = (const float*)d_in[6];
  const float* Wo  = (const float*)d_in[7];
  const float* bo  = (const float*)d_in[8];
  const float* g1t = (const float*)d_in[9];
  const float* b1t = (const float*)d_in[10];
  const float* g1s = (const float*)d_in[11];
  const float* b1s = (const float*)d_in[12];
  const float* W1  = (const float*)d_in[13];
  const float* bf1 = (const float*)d_in[14];
  const float* W2  = (const float*)d_in[15];
  const float* bf2 = (const float*)d_in[16];
  const float* g2t = (const float*)d_in[17];
  const float* b2t = (const float*)d_in[18];
  const float* g2s = (const float*)d_in[19];
  const float* b2s = (const float*)d_in[20];

  char* ws = (char*)d_ws;
  unsigned short* xb  = (unsigned short*)(ws);                 // 16384x128 bf16
  unsigned short* wqT = (unsigned short*)(ws + 4194304);
  unsigned short* wkT = wqT + 16384;
  unsigned short* wvT = wkT + 16384;
  unsigned short* woT = wvT + 16384;
  unsigned short* w1T = woT + 16384;   // [512][128]
  unsigned short* w2T = w1T + 65536;   // [128][512]
  unsigned short* qb  = w2T + 65536;   // [8][4][2048][32]
  unsigned short* kb  = qb + 2097152;
  unsigned short* vT  = kb + 2097152;  // [8][4][32][2048]
  unsigned short* ao  = vT + 2097152;  // [16384][128]
  float* outp = (float*)d_out;

  prep_kernel<<<1792, 256, 0, stream>>>(x, Wq, Wk, Wv, Wo, W1, W2,
                                        xb, wqT, wkT, wvT, woT, w1T, w2T);
  qkv_kernel<<<dim3(256, 3), 256, 0, stream>>>(xb, wqT, wkT, wvT, bq, bk, bv, qb, kb, vT);
  attn_kernel<<<dim3(32, 32), 512, 0, stream>>>(qb, kb, vT, ao);
  tail_kernel<<<512, 512, 0, stream>>>(ao, woT, bo, x, g1t, b1t, g1s, b1s,
                                       w1T, bf1, w2T, bf2, g2t, b2t, g2s, b2s, outp);
}